// Round 3
// baseline (388.301 us; speedup 1.0000x reference)
//
#include <hip/hip_runtime.h>

// Problem constants (from reference: B=256, S=64, R=128, F=1536, D=256)
constexpr int Bc = 256;
constexpr int Sc = 64;
constexpr int Rc = 128;
constexpr int Fc = 1536;
constexpr int Dc = 256;  // F/6

// One fused kernel. Grid = B * (R/16) = 2048 blocks, 256 threads.
// Block (b, chunk) owns rows r0 = chunk*16 .. r0+15 of batch b.
//  Phase 1: per-row stats over F axis (wave w handles rows r0+4w .. r0+4w+3):
//    s0[r] = sum_d r_re*(h_re*t_re + h_im*t_im) + r_im*(h_re*t_im - h_im*t_re)
//    q[r]  = sum_f tri[b,r,f]^2
//  Phase 2: for its 16 r and all 64 s:
//    a = (alpha-0.1)*mask;  sp += softplus(-a^3*s0);  aq += a^2*q
//  Block reduce -> double atomicAdd into acc[0..1]; last block finalizes:
//    out = acc0/numtrue + 0.01*acc1/(B*S*R*D)

__device__ __forceinline__ void accum_term(float h_re, float h_im,
                                           float r_re, float r_im,
                                           float t_re, float t_im,
                                           float& s0, float& q) {
  s0 += r_re * (h_re * t_re + h_im * t_im) + r_im * (h_re * t_im - h_im * t_re);
  q  += h_re * h_re + h_im * h_im + r_re * r_re + r_im * r_im + t_re * t_re + t_im * t_im;
}

__global__ __launch_bounds__(256) void fused_kernel(
    const float* __restrict__ tri, const float* __restrict__ alpha,
    const float* __restrict__ mask, double* __restrict__ acc,
    unsigned int* __restrict__ counter, float* __restrict__ out) {
  const int wid  = threadIdx.x >> 6;   // wave id (0..3)
  const int lane = threadIdx.x & 63;
  const int b     = blockIdx.x >> 3;         // batch index
  const int r0    = (blockIdx.x & 7) * 16;   // first r of this block's chunk

  __shared__ float s0_lds[16];
  __shared__ float q_lds[16];

  // ---- Phase 1: row stats. Wave w -> rows r0+4w+j, j=0..3 ----
  #pragma unroll
  for (int j = 0; j < 4; ++j) {
    const int r = r0 + wid * 4 + j;
    const float4* p4 =
        reinterpret_cast<const float4*>(tri + ((size_t)b * Rc + r) * Fc);
    const float4 hre = p4[lane +   0];
    const float4 him = p4[lane +  64];
    const float4 rre = p4[lane + 128];
    const float4 rim = p4[lane + 192];
    const float4 tre = p4[lane + 256];
    const float4 tim = p4[lane + 320];

    float s0 = 0.f, q = 0.f;
    accum_term(hre.x, him.x, rre.x, rim.x, tre.x, tim.x, s0, q);
    accum_term(hre.y, him.y, rre.y, rim.y, tre.y, tim.y, s0, q);
    accum_term(hre.z, him.z, rre.z, rim.z, tre.z, tim.z, s0, q);
    accum_term(hre.w, him.w, rre.w, rim.w, tre.w, tim.w, s0, q);

    #pragma unroll
    for (int off = 32; off > 0; off >>= 1) {
      s0 += __shfl_down(s0, off, 64);
      q  += __shfl_down(q, off, 64);
    }
    if (lane == 0) {
      s0_lds[wid * 4 + j] = s0;
      q_lds[wid * 4 + j]  = q;
    }
  }
  __syncthreads();

  // ---- Phase 2: score + regul over (s, r-chunk) ----
  // thread t: s = t>>2, r-quad = t&3 -> float4 over r
  const int s  = threadIdx.x >> 2;
  const int rq = threadIdx.x & 3;
  const float m = mask[b * Sc + s];
  const float4 al = *reinterpret_cast<const float4*>(
      alpha + ((size_t)b * Sc + s) * Rc + r0 + rq * 4);

  float sp_sum = 0.f, aq_sum = 0.f;
  const float av[4] = {al.x, al.y, al.z, al.w};
  #pragma unroll
  for (int j = 0; j < 4; ++j) {
    const int rl = rq * 4 + j;
    const float a  = (av[j] - 0.1f) * m;
    const float sc = -(a * a * a) * s0_lds[rl];
    sp_sum += fmaxf(sc, 0.f) + log1pf(__expf(-fabsf(sc)));
    aq_sum += a * a * q_lds[rl];
  }

  // ---- block reduce (4 waves) ----
  #pragma unroll
  for (int off = 32; off > 0; off >>= 1) {
    sp_sum += __shfl_down(sp_sum, off, 64);
    aq_sum += __shfl_down(aq_sum, off, 64);
  }
  __shared__ float red[8];
  __shared__ bool last_block;
  if (lane == 0) {
    red[wid]     = sp_sum;
    red[wid + 4] = aq_sum;
  }
  __syncthreads();
  if (threadIdx.x == 0) {
    const float spb = red[0] + red[1] + red[2] + red[3];
    const float aqb = red[4] + red[5] + red[6] + red[7];
    atomicAdd(acc + 0, (double)spb);
    atomicAdd(acc + 1, (double)aqb);
    __threadfence();
    const unsigned done = atomicAdd(counter, 1u);
    last_block = (done == gridDim.x - 1);
  }
  __syncthreads();

  // ---- finalize in the last block ----
  if (last_block) {
    float msum = 0.f;
    for (int i = threadIdx.x; i < Bc * Sc; i += 256) msum += mask[i];
    #pragma unroll
    for (int off = 32; off > 0; off >>= 1) msum += __shfl_down(msum, off, 64);
    __shared__ float mred[4];
    if (lane == 0) mred[wid] = msum;
    __syncthreads();
    if (threadIdx.x == 0) {
      const double numtrue = (double)(mred[0] + mred[1] + mred[2] + mred[3]);
      // atomic reads to dodge any stale-L2 hazard across XCDs (G16)
      const double sp = atomicAdd(acc + 0, 0.0);
      const double aq = atomicAdd(acc + 1, 0.0);
      const double denom = (double)Bc * Sc * Rc * Dc;
      out[0] = (float)(sp / numtrue + 0.01 * aq / denom);
    }
  }
}

extern "C" void kernel_launch(void* const* d_in, const int* in_sizes, int n_in,
                              void* d_out, int out_size, void* d_ws, size_t ws_size,
                              hipStream_t stream) {
  const float* tri   = (const float*)d_in[0];  // (B, R, F)
  const float* alpha = (const float*)d_in[1];  // (B, S, R)
  const float* mask  = (const float*)d_in[2];  // (B, S)
  float* out = (float*)d_out;

  // ws layout: acc[0..1] doubles, counter at +16; zero first 64 B
  double*       acc     = (double*)d_ws;
  unsigned int* counter = (unsigned int*)((char*)d_ws + 16);

  hipMemsetAsync(d_ws, 0, 64, stream);
  fused_kernel<<<Bc * (Rc / 16), 256, 0, stream>>>(tri, alpha, mask, acc,
                                                   counter, out);
}

// Round 4
// 283.547 us; speedup vs baseline: 1.3694x; 1.3694x over previous
//
#include <hip/hip_runtime.h>

// Problem constants (from reference: B=256, S=64, R=128, F=1536, D=256)
constexpr int Bc = 256;
constexpr int Sc = 64;
constexpr int Rc = 128;
constexpr int Fc = 1536;
constexpr int Dc = 256;  // F/6

// ---------------------------------------------------------------------------
// Kernel 1: per-row (b,r) statistics over the F=1536 axis. Pure streaming,
// no atomics. One wave per row, 6 independent float4 loads per lane.
// ---------------------------------------------------------------------------
__device__ __forceinline__ void accum_term(float h_re, float h_im,
                                           float r_re, float r_im,
                                           float t_re, float t_im,
                                           float& s0, float& q) {
  s0 += r_re * (h_re * t_re + h_im * t_im) + r_im * (h_re * t_im - h_im * t_re);
  q  += h_re * h_re + h_im * h_im + r_re * r_re + r_im * r_im + t_re * t_re + t_im * t_im;
}

__global__ __launch_bounds__(256) void rowstats_kernel(
    const float* __restrict__ tri, float* __restrict__ s0_out,
    float* __restrict__ q_out) {
  const int wid  = threadIdx.x >> 6;
  const int lane = threadIdx.x & 63;
  const int row  = blockIdx.x * 4 + wid;  // (b*R + r) < B*R

  const float4* p4 = reinterpret_cast<const float4*>(tri + (size_t)row * Fc);
  const float4 hre = p4[lane +   0];
  const float4 him = p4[lane +  64];
  const float4 rre = p4[lane + 128];
  const float4 rim = p4[lane + 192];
  const float4 tre = p4[lane + 256];
  const float4 tim = p4[lane + 320];

  float s0 = 0.f, q = 0.f;
  accum_term(hre.x, him.x, rre.x, rim.x, tre.x, tim.x, s0, q);
  accum_term(hre.y, him.y, rre.y, rim.y, tre.y, tim.y, s0, q);
  accum_term(hre.z, him.z, rre.z, rim.z, tre.z, tim.z, s0, q);
  accum_term(hre.w, him.w, rre.w, rim.w, tre.w, tim.w, s0, q);

  #pragma unroll
  for (int off = 32; off > 0; off >>= 1) {
    s0 += __shfl_down(s0, off, 64);
    q  += __shfl_down(q, off, 64);
  }
  if (lane == 0) {
    s0_out[row] = s0;
    q_out[row]  = q;
  }
}

// ---------------------------------------------------------------------------
// Kernel 2: score + regul partials over (b,s,r). NO atomics, NO fence:
// each block writes one float2 partial {sp_sum, aq_sum} to part[blockIdx].
// ---------------------------------------------------------------------------
__global__ __launch_bounds__(256) void score_kernel(
    const float* __restrict__ alpha, const float* __restrict__ mask,
    const float* __restrict__ s0_arr, const float* __restrict__ q_arr,
    float2* __restrict__ part) {
  const int t   = blockIdx.x * 256 + threadIdx.x;
  const int idx = t * 4;              // flat (B,S,R)
  const int r   = idx & (Rc - 1);
  const int bs  = idx >> 7;
  const int b   = bs >> 6;

  const float m = mask[bs];
  const float4 al  = *reinterpret_cast<const float4*>(alpha + idx);
  const float4 s0v = *reinterpret_cast<const float4*>(s0_arr + b * Rc + r);
  const float4 qv  = *reinterpret_cast<const float4*>(q_arr + b * Rc + r);

  float sp_sum = 0.f, aq_sum = 0.f;
  const float av[4] = {al.x, al.y, al.z, al.w};
  const float sv[4] = {s0v.x, s0v.y, s0v.z, s0v.w};
  const float qvv[4] = {qv.x, qv.y, qv.z, qv.w};
  #pragma unroll
  for (int j = 0; j < 4; ++j) {
    const float a  = (av[j] - 0.1f) * m;
    const float sc = -(a * a * a) * sv[j];
    sp_sum += fmaxf(sc, 0.f) + log1pf(__expf(-fabsf(sc)));
    aq_sum += a * a * qvv[j];
  }

  #pragma unroll
  for (int off = 32; off > 0; off >>= 1) {
    sp_sum += __shfl_down(sp_sum, off, 64);
    aq_sum += __shfl_down(aq_sum, off, 64);
  }
  __shared__ float red[8];
  const int lane = threadIdx.x & 63, wid = threadIdx.x >> 6;
  if (lane == 0) {
    red[wid]     = sp_sum;
    red[wid + 4] = aq_sum;
  }
  __syncthreads();
  if (threadIdx.x == 0) {
    part[blockIdx.x] =
        make_float2(red[0] + red[1] + red[2] + red[3],
                    red[4] + red[5] + red[6] + red[7]);
  }
}

// ---------------------------------------------------------------------------
// Kernel 3: finalize (1 block). Reduce 2048 partials + mask sum, combine.
// ---------------------------------------------------------------------------
__global__ __launch_bounds__(256) void finalize_kernel(
    const float* __restrict__ mask, const float2* __restrict__ part,
    float* __restrict__ out) {
  double sp = 0.0, aq = 0.0;
  float msum = 0.f;
  #pragma unroll
  for (int j = 0; j < 8; ++j) {          // 2048 partials / 256 threads
    const float2 p = part[threadIdx.x + j * 256];
    sp += (double)p.x;
    aq += (double)p.y;
  }
  const float4* m4 = reinterpret_cast<const float4*>(mask);
  #pragma unroll
  for (int j = 0; j < 16; ++j) {         // 4096 float4 / 256 threads
    const float4 v = m4[threadIdx.x + j * 256];
    msum += v.x + v.y + v.z + v.w;
  }

  #pragma unroll
  for (int off = 32; off > 0; off >>= 1) {
    sp   += __shfl_down(sp, off, 64);
    aq   += __shfl_down(aq, off, 64);
    msum += __shfl_down(msum, off, 64);
  }
  __shared__ double dred[8];
  __shared__ float fred[4];
  const int lane = threadIdx.x & 63, wid = threadIdx.x >> 6;
  if (lane == 0) {
    dred[wid]     = sp;
    dred[wid + 4] = aq;
    fred[wid]     = msum;
  }
  __syncthreads();
  if (threadIdx.x == 0) {
    const double spt = dred[0] + dred[1] + dred[2] + dred[3];
    const double aqt = dred[4] + dred[5] + dred[6] + dred[7];
    const double numtrue = (double)(fred[0] + fred[1] + fred[2] + fred[3]);
    const double denom = (double)Bc * Sc * Rc * Dc;
    out[0] = (float)(spt / numtrue + 0.01 * aqt / denom);
  }
}

// ---------------------------------------------------------------------------
extern "C" void kernel_launch(void* const* d_in, const int* in_sizes, int n_in,
                              void* d_out, int out_size, void* d_ws, size_t ws_size,
                              hipStream_t stream) {
  const float* tri   = (const float*)d_in[0];  // (B, R, F)
  const float* alpha = (const float*)d_in[1];  // (B, S, R)
  const float* mask  = (const float*)d_in[2];  // (B, S)
  float* out = (float*)d_out;

  // ws layout (all fully overwritten before read; no zeroing needed):
  //   s0[B*R] floats | q[B*R] floats | part[2048] float2
  float*  s0_arr = (float*)d_ws;
  float*  q_arr  = s0_arr + Bc * Rc;
  float2* part   = (float2*)(q_arr + Bc * Rc);

  rowstats_kernel<<<(Bc * Rc) / 4, 256, 0, stream>>>(tri, s0_arr, q_arr);
  score_kernel<<<(Bc * Sc * Rc) / (4 * 256), 256, 0, stream>>>(alpha, mask,
                                                               s0_arr, q_arr, part);
  finalize_kernel<<<1, 256, 0, stream>>>(mask, part, out);
}